// Round 7
// baseline (246.961 us; speedup 1.0000x reference)
//
#include <hip/hip_runtime.h>
#include <math.h>

#define BATCH 8
#define SEQ   4096
#define DIM   64
#define LQ    2744            // int((1-0.33)*4096)
#define QPB   128             // queries per attn block (2 waves x 64)
#define NQB   22              // ceil(2744/128)
#define QPAD  2816            // NQB*QPB
#define KS    8               // key splits (512 keys per block)
#define QSC   0.1803368801111204f   // 0.125 * log2(e), folded into Qh

typedef _Float16 half8 __attribute__((ext_vector_type(8)));
typedef __fp16   fp16x2 __attribute__((ext_vector_type(2)));
typedef float    fx16  __attribute__((ext_vector_type(16)));
typedef unsigned short ushort_t;

union UHF { unsigned u[4]; uint4 u4; half8 h; };

__device__ __forceinline__ unsigned pack_f16(float a, float b) {
    fp16x2 r = __builtin_amdgcn_cvt_pkrtz(a, b);   // v_cvt_pkrtz_f16_f32
    union { fp16x2 h; unsigned u; } cv; cv.h = r; return cv.u;
}

// ---------------- sortable-uint mapping ----------------
__device__ __forceinline__ unsigned f2sort(float f) {
    unsigned u = __float_as_uint(f);
    return (u & 0x80000000u) ? ~u : (u | 0x80000000u);
}
__device__ __forceinline__ float sort2f(unsigned u) {
    return __uint_as_float((u & 0x80000000u) ? (u & 0x7FFFFFFFu) : ~u);
}

// ---------------- radix select: k-th largest of 4096 --------------------
// Ballot-aggregated histogram (one atomic per distinct bin per wave-pass)
// + wave-shuffle suffix scan (4 barriers/pass).
// res[0] = key of k-th largest; res[1] = #elems equal to key in the top-k.
template <int NT>
__device__ void radix_select_4096(const unsigned* u, int k, unsigned* hist,
                                  unsigned* wtot, unsigned* res) {
    const int t = threadIdx.x;
    const int lane = t & 63, wv = t >> 6;
    if (t == 0) { res[0] = 0u; res[1] = (unsigned)k; }
    for (int pass = 3; pass >= 0; --pass) {
        const int shift = pass * 8;
        if (t < 256) hist[t] = 0u;
        __syncthreads();
        const unsigned pref  = res[0];
        const unsigned kk    = res[1];
        const unsigned hmask = (pass == 3) ? 0u : (0xFFFFFFFFu << (shift + 8));
        for (int i = t; i < 4096; i += NT) {
            const unsigned ui = u[i];
            const bool part = (ui & hmask) == pref;
            const unsigned bin = (ui >> shift) & 255u;
            unsigned long long m = __ballot(part);
#pragma unroll
            for (int j = 0; j < 8; ++j) {
                unsigned long long bj = __ballot(part && ((bin >> j) & 1u));
                m &= ((bin >> j) & 1u) ? bj : ~bj;
            }
            // leader = lowest set lane of m does one aggregated atomic
            if (part && (1ull << lane) == (m & (0ull - m)))
                atomicAdd(&hist[bin], (unsigned)__popcll(m));
        }
        __syncthreads();
        unsigned h = 0u, s = 0u;
        if (t < 256) {
            h = hist[t]; s = h;
#pragma unroll
            for (int ofs = 1; ofs < 64; ofs <<= 1) {   // wave suffix scan
                unsigned o = __shfl_down(s, ofs, 64);
                if (lane + ofs < 64) s += o;
            }
            if (lane == 0) wtot[wv] = s;
        }
        __syncthreads();
        if (t < 256) {
            unsigned add = 0u;
            for (int j = wv + 1; j < 4; ++j) add += wtot[j];
            s += add;                         // inclusive suffix sum bins t..255
            if (s >= kk && (s - h) < kk) {    // unique threshold bin
                res[0] = pref | ((unsigned)t << shift);
                res[1] = kk - (s - h);
            }
        }
        __syncthreads();
    }
}

// ---------------- K1: projections -------------------
// Q fp32 (selection path), Kt fp32 (channel top-k), Qh f16 scaled, Kh f16,
// Vt f16 transposed+k-permuted (PV B-fragment order), pmean partial V sums.
__global__ __launch_bounds__(256) void proj_kernel(
    const float* __restrict__ x,  const float* __restrict__ Wq,
    const float* __restrict__ Wk, const float* __restrict__ Wv,
    float* __restrict__ Q, float* __restrict__ Kt,
    _Float16* __restrict__ Qh, _Float16* __restrict__ Kh,
    ushort_t* __restrict__ Vt, float* __restrict__ pmean) {
    const int rt = blockIdx.x, b = blockIdx.y, t = threadIdx.x;
    __shared__ float4 xs4[64 * 17];
    __shared__ float  red[4][64];
    {
        const float4* xg = (const float4*)(x + ((size_t)b * SEQ + rt * 64) * DIM);
        for (int i = 0; i < 4; ++i) {
            int s = t + 256 * i;
            xs4[(s >> 4) * 17 + (s & 15)] = xg[s];
        }
    }
    __syncthreads();
    const int ch = t & 63, rg = t >> 6;
    float accq[16], acck[16], accv[16];
#pragma unroll
    for (int i = 0; i < 16; ++i) { accq[i] = 0.f; acck[i] = 0.f; accv[i] = 0.f; }
    for (int dc = 0; dc < 4; ++dc) {
        float wq[16], wk[16], wv[16];
#pragma unroll
        for (int dd = 0; dd < 16; ++dd) {
            int d = dc * 16 + dd;
            wq[dd] = Wq[d * 64 + ch]; wk[dd] = Wk[d * 64 + ch]; wv[dd] = Wv[d * 64 + ch];
        }
        for (int r = 0; r < 16; ++r) {
            const float4* xr = &xs4[(rg * 16 + r) * 17 + dc * 4];
            float xv[16];
            float4 a0 = xr[0], a1 = xr[1], a2 = xr[2], a3 = xr[3];
            xv[0]=a0.x; xv[1]=a0.y; xv[2]=a0.z; xv[3]=a0.w;
            xv[4]=a1.x; xv[5]=a1.y; xv[6]=a1.z; xv[7]=a1.w;
            xv[8]=a2.x; xv[9]=a2.y; xv[10]=a2.z; xv[11]=a2.w;
            xv[12]=a3.x; xv[13]=a3.y; xv[14]=a3.z; xv[15]=a3.w;
#pragma unroll
            for (int dd = 0; dd < 16; ++dd) {
                accq[r] = fmaf(xv[dd], wq[dd], accq[r]);
                acck[r] = fmaf(xv[dd], wk[dd], acck[r]);
                accv[r] = fmaf(xv[dd], wv[dd], accv[r]);
            }
        }
    }
    const int rowbase = rt * 64 + rg * 16;
    float sv = 0.f;
#pragma unroll
    for (int r = 0; r < 16; ++r) {
        size_t o = ((size_t)b * SEQ + rowbase + r) * DIM + ch;
        Q[o]  = accq[r];
        Qh[o] = (_Float16)(accq[r] * QSC);
        Kh[o] = (_Float16)acck[r];
        sv += accv[r];
    }
    float4* ktp = (float4*)(Kt + ((size_t)b * 64 + ch) * SEQ + rowbase);
    ktp[0] = make_float4(acck[0], acck[1], acck[2], acck[3]);
    ktp[1] = make_float4(acck[4], acck[5], acck[6], acck[7]);
    ktp[2] = make_float4(acck[8], acck[9], acck[10], acck[11]);
    ktp[3] = make_float4(acck[12], acck[13], acck[14], acck[15]);
    // Vt f16, k-permuted pair order within each 16-group: [0,1,4,5,2,3,6,7]
    {
        unsigned pk[8];
#pragma unroll
        for (int i = 0; i < 8; ++i) pk[i] = pack_f16(accv[2*i], accv[2*i+1]);
        uint4* vp = (uint4*)(Vt + ((size_t)(b * 64 + ch)) * SEQ + rowbase);
        vp[0] = make_uint4(pk[0], pk[1], pk[4], pk[5]);
        vp[1] = make_uint4(pk[2], pk[3], pk[6], pk[7]);
    }
    red[rg][ch] = sv;
    __syncthreads();
    if (rg == 0)
        pmean[((size_t)b * 64 + ch) * 64 + rt] =
            red[0][ch] + red[1][ch] + red[2][ch] + red[3][ch];
}

// ---------------- K2: K_reduce = mean of top-LQ per (b,ch); V-mean agg ---
__global__ __launch_bounds__(256) void kmean_kernel(const float* __restrict__ Kt,
                                                    const float* __restrict__ pmean,
                                                    float* __restrict__ Kred,
                                                    float* __restrict__ meanfin) {
    __shared__ unsigned u[4096];
    __shared__ unsigned hist[256];
    __shared__ unsigned wtot[4];
    __shared__ unsigned res[2];
    __shared__ float rsum[4];
    const int bc = blockIdx.x, t = threadIdx.x;
    if (t < 64) {   // V-mean aggregation: wave 0 sums the 64 partials
        float v = pmean[(size_t)bc * 64 + t];
        for (int m = 1; m < 64; m <<= 1) v += __shfl_xor(v, m, 64);
        if (t == 0) meanfin[bc] = v * (1.0f / (float)SEQ);
    }
    const float4* c4 = (const float4*)(Kt + (size_t)bc * SEQ);
    for (int i = t; i < 1024; i += 256) {
        float4 v = c4[i];
        u[i*4+0] = f2sort(v.x); u[i*4+1] = f2sort(v.y);
        u[i*4+2] = f2sort(v.z); u[i*4+3] = f2sort(v.w);
    }
    __syncthreads();
    radix_select_4096<256>(u, LQ, hist, wtot, res);
    const unsigned Tu = res[0];
    const int krem = (int)res[1];
    float loc = 0.f;
    for (int i = t; i < 4096; i += 256)
        if (u[i] > Tu) loc += sort2f(u[i]);
    for (int msk = 1; msk < 64; msk <<= 1) loc += __shfl_xor(loc, msk, 64);
    if ((t & 63) == 0) rsum[t >> 6] = loc;
    __syncthreads();
    if (t == 0) {
        float s = rsum[0] + rsum[1] + rsum[2] + rsum[3] + (float)krem * sort2f(Tu);
        Kred[bc] = s / (float)LQ;
    }
}

// ---------------- K3: fused sqk + per-batch top-LQ selection -------------
__global__ __launch_bounds__(1024) void select_kernel(const float* __restrict__ Q,
                                                      const float* __restrict__ Kred,
                                                      int* __restrict__ sel,
                                                      int* __restrict__ inv) {
    __shared__ unsigned u[4096];
    __shared__ unsigned hist[256];
    __shared__ unsigned wtot[4];
    __shared__ unsigned res[2];
    __shared__ float kr[64];
    __shared__ int eq_idx[256];
    __shared__ int cnts[2];
    const int b = blockIdx.x, t = threadIdx.x;
    if (t < 64) kr[t] = Kred[b * 64 + t];
    if (t < 2) cnts[t] = 0;
    int* invb = inv + (size_t)b * SEQ;
    __syncthreads();
    for (int row = t; row < 4096; row += 1024) {   // sqk inline (fp32-exact)
        const float4* q = (const float4*)(Q + ((size_t)b * SEQ + row) * DIM);
        float s = 0.f;
#pragma unroll
        for (int i = 0; i < 16; ++i) {
            float4 v = q[i];
            s = fmaf(v.x, kr[i*4+0], s); s = fmaf(v.y, kr[i*4+1], s);
            s = fmaf(v.z, kr[i*4+2], s); s = fmaf(v.w, kr[i*4+3], s);
        }
        u[row] = f2sort(s);
        invb[row] = -1;
    }
    __syncthreads();
    radix_select_4096<1024>(u, LQ, hist, wtot, res);
    const unsigned Tu = res[0];
    const int krem = (int)res[1];
    int* selb = sel + b * QPAD;
    for (int i = t; i < 4096; i += 1024) {
        unsigned ui = u[i];
        if (ui > Tu) {
            int p = atomicAdd(&cnts[0], 1);
            selb[p] = i;
            invb[i] = p;
        } else if (ui == Tu) {
            int p = atomicAdd(&cnts[1], 1);
            if (p < 256) eq_idx[p] = i;
        }
    }
    __syncthreads();
    if (t == 0) {
        int ng = cnts[0];
        int ne = cnts[1] < 256 ? cnts[1] : 256;
        for (int i = 1; i < ne; ++i) {          // ties ~unique floats: ne≈1
            int v = eq_idx[i], j = i - 1;
            while (j >= 0 && eq_idx[j] > v) { eq_idx[j+1] = eq_idx[j]; --j; }
            eq_idx[j+1] = v;
        }
        for (int j = 0; j < krem; ++j) {
            selb[ng + j] = eq_idx[j];
            invb[eq_idx[j]] = ng + j;
        }
    }
    __syncthreads();
    if (t < QPAD - LQ) selb[LQ + t] = selb[LQ - 1];   // pad (parallel)
}

// ---------------- K4: MFMA flash attention, 64 q/wave --------------------
// 2-wave blocks; each wave owns 64 queries (two 32-col blocks a,b), so K/V
// fragments amortize over 2x MFMA and every chain (Sa,Sb,Oa0,Oa1,Ob0,Ob1)
// is 2-wide ILP. P and V in f16 (scores bounded; P <= 2^11 << 65504).
// KS=8 key splits; merge via global fp32 atomicAdd into zeroed pout/pl.
__global__ __launch_bounds__(128, 2) void attn_kernel(
    const ushort_t* __restrict__ Qh, const ushort_t* __restrict__ Kh,
    const ushort_t* __restrict__ Vt, const int* __restrict__ sel,
    float* __restrict__ pl, float* __restrict__ pout) {
    const int qt = blockIdx.x, ks = blockIdx.y, b = blockIdx.z;
    const int t = threadIdx.x, w = t >> 6, lane = t & 63;
    const int col = lane & 31, h = lane >> 5;

    __shared__ ushort_t Ktile[2][32 * 64];
    __shared__ ushort_t Vtile[2][32 * 64];

    // persistent Q fragments for the two q-blocks (B-operand layout)
    half8 qfa[4], qfb[4];
    const int qbase = qt * QPB + w * 64;
    {
        const int rowa = sel[b * QPAD + qbase + col];
        const int rowb = sel[b * QPAD + qbase + 32 + col];
        const uint4* qga = (const uint4*)(Qh + ((size_t)b * SEQ + rowa) * DIM);
        const uint4* qgb = (const uint4*)(Qh + ((size_t)b * SEQ + rowb) * DIM);
#pragma unroll
        for (int m = 0; m < 4; ++m) {
            UHF ua, ub;
            ua.u4 = qga[2 * m + h]; qfa[m] = ua.h;
            ub.u4 = qgb[2 * m + h]; qfb[m] = ub.h;
        }
    }

    // loop-invariant swizzled LDS offsets (ushort elements)
    int koff[4], voff[4];
#pragma unroll
    for (int m = 0; m < 4; ++m)
        koff[m] = col * 64 + 8 * ((2 * m + h) ^ (col & 7));
#pragma unroll
    for (int i = 0; i < 4; ++i)
        voff[i] = col * 64 + 8 * ((i * 2 + h) ^ (col & 7));   // i=2D+c

    fx16 Oa0, Oa1, Ob0, Ob1;
#pragma unroll
    for (int r = 0; r < 16; ++r) { Oa0[r]=0.f; Oa1[r]=0.f; Ob0[r]=0.f; Ob1[r]=0.f; }
    float la = 0.f, lb = 0.f;

    // staging: each of 128 threads stages 2 K granules + 2 V granules
    const int srow = t >> 3, sgr = t & 7;          // srow 0..15
    const int lg = sgr ^ (srow & 7);               // same for srow+16
    const int vD = lg >> 2, vc = (lg >> 1) & 1, vh = lg & 1;
    const ushort_t* kp0 = Kh + ((size_t)b * SEQ + ks * 512 + srow) * DIM + 8 * lg;
    const ushort_t* kp1 = kp0 + 16 * DIM;
    const ushort_t* vp0 = Vt + ((size_t)(b * DIM + srow + 32 * vD)) * SEQ
                          + ks * 512 + vc * 16 + vh * 8;
    const ushort_t* vp1 = vp0 + 16 * SEQ;

    uint4 kr0 = *(const uint4*)kp0, kr1 = *(const uint4*)kp1;
    uint4 vr0 = *(const uint4*)vp0, vr1 = *(const uint4*)vp1;

    for (int tile = 0; tile < 16; ++tile) {
        const int buf = tile & 1;
        *(uint4*)&Ktile[buf][srow * 64 + sgr * 8]        = kr0;
        *(uint4*)&Ktile[buf][(srow + 16) * 64 + sgr * 8] = kr1;
        *(uint4*)&Vtile[buf][srow * 64 + sgr * 8]        = vr0;
        *(uint4*)&Vtile[buf][(srow + 16) * 64 + sgr * 8] = vr1;
        __syncthreads();
        if (tile < 15) {   // prefetch next tile during compute
            kp0 += 32 * DIM; kp1 += 32 * DIM; vp0 += 32; vp1 += 32;
            kr0 = *(const uint4*)kp0; kr1 = *(const uint4*)kp1;
            vr0 = *(const uint4*)vp0; vr1 = *(const uint4*)vp1;
        }
        // S^T tiles (two independent 4-MFMA chains)
        fx16 Sa, Sb;
#pragma unroll
        for (int r = 0; r < 16; ++r) { Sa[r] = 0.f; Sb[r] = 0.f; }
        UHF kf[4];
#pragma unroll
        for (int m = 0; m < 4; ++m)
            kf[m].u4 = *(const uint4*)&Ktile[buf][koff[m]];
#pragma unroll
        for (int m = 0; m < 4; ++m) {
            Sa = __builtin_amdgcn_mfma_f32_32x32x16_f16(kf[m].h, qfa[m], Sa, 0, 0, 0);
            Sb = __builtin_amdgcn_mfma_f32_32x32x16_f16(kf[m].h, qfb[m], Sb, 0, 0, 0);
        }
        // exp2 + f16 pack + row-sum (P = exp2(S); no max: scores bounded)
        UHF Aa0, Aa1, Ab0, Ab1;
#pragma unroll
        for (int v = 0; v < 4; ++v) {
            float a0 = __builtin_amdgcn_exp2f(Sa[2*v]);
            float a1 = __builtin_amdgcn_exp2f(Sa[2*v+1]);
            float a2 = __builtin_amdgcn_exp2f(Sa[8+2*v]);
            float a3 = __builtin_amdgcn_exp2f(Sa[8+2*v+1]);
            la += (a0 + a1) + (a2 + a3);
            Aa0.u[v] = pack_f16(a0, a1);
            Aa1.u[v] = pack_f16(a2, a3);
            float b0 = __builtin_amdgcn_exp2f(Sb[2*v]);
            float b1 = __builtin_amdgcn_exp2f(Sb[2*v+1]);
            float b2 = __builtin_amdgcn_exp2f(Sb[8+2*v]);
            float b3 = __builtin_amdgcn_exp2f(Sb[8+2*v+1]);
            lb += (b0 + b1) + (b2 + b3);
            Ab0.u[v] = pack_f16(b0, b1);
            Ab1.u[v] = pack_f16(b2, b3);
        }
        // O += P * V (f16 MFMA, 4 independent accumulator chains)
        UHF vf[4];
#pragma unroll
        for (int i = 0; i < 4; ++i)
            vf[i].u4 = *(const uint4*)&Vtile[buf][voff[i]];
        Oa0 = __builtin_amdgcn_mfma_f32_32x32x16_f16(Aa0.h, vf[0].h, Oa0, 0, 0, 0);
        Ob0 = __builtin_amdgcn_mfma_f32_32x32x16_f16(Ab0.h, vf[0].h, Ob0, 0, 0, 0);
        Oa0 = __builtin_amdgcn_mfma_f32_32x32x16_f16(Aa1.h, vf[1].h, Oa0, 0, 0, 0);
        Ob0 = __builtin_amdgcn_mfma_f32_32x32x16_f16(Ab1.h, vf[1].h, Ob0, 0, 0, 0);
        Oa1 = __builtin_amdgcn_mfma_f32_32x32x16_f16(Aa0.h, vf[2].h, Oa1, 0, 0, 0);
        Ob1 = __builtin_amdgcn_mfma_f32_32x32x16_f16(Ab0.h, vf[2].h, Ob1, 0, 0, 0);
        Oa1 = __builtin_amdgcn_mfma_f32_32x32x16_f16(Aa1.h, vf[3].h, Oa1, 0, 0, 0);
        Ob1 = __builtin_amdgcn_mfma_f32_32x32x16_f16(Ab1.h, vf[3].h, Ob1, 0, 0, 0);
    }

    la += __shfl_xor(la, 32);   // combine the two k-halves per column
    lb += __shfl_xor(lb, 32);

    const size_t base = (size_t)b * QPAD + qbase;
#pragma unroll
    for (int r = 0; r < 16; ++r) {
        const int q = (r & 3) + 8 * (r >> 2) + 4 * h;
        atomicAdd(&pout[(base + q) * DIM + col],           Oa0[r]);
        atomicAdd(&pout[(base + q) * DIM + 32 + col],      Oa1[r]);
        atomicAdd(&pout[(base + 32 + q) * DIM + col],      Ob0[r]);
        atomicAdd(&pout[(base + 32 + q) * DIM + 32 + col], Ob1[r]);
    }
    if (h == 0) {
        atomicAdd(&pl[base + col], la);
        atomicAdd(&pl[base + 32 + col], lb);
    }
}

// ---------------- K5: normalize+scatter OR mean-fill, one pass -----------
__global__ __launch_bounds__(256) void comb_kernel(
    const float* __restrict__ pl, const float* __restrict__ pout,
    const int* __restrict__ inv, const float* __restrict__ meanfin,
    float* __restrict__ out) {
    const int idx = blockIdx.x * 256 + threadIdx.x;   // over BATCH*SEQ*16
    const int b = idx >> 16;
    const int rc = idx & 65535;
    const int row = rc >> 4, c = rc & 15;
    const int p = inv[b * SEQ + row];
    float4 o;
    if (p >= 0) {
        const size_t s0 = (size_t)b * QPAD + p;
        const float invl = 1.0f / pl[s0];
        float4 a = ((const float4*)(pout + s0 * DIM))[c];
        o = make_float4(a.x * invl, a.y * invl, a.z * invl, a.w * invl);
    } else {
        o = make_float4(meanfin[b * 64 + c * 4 + 0], meanfin[b * 64 + c * 4 + 1],
                        meanfin[b * 64 + c * 4 + 2], meanfin[b * 64 + c * 4 + 3]);
    }
    ((float4*)out)[idx] = o;
}

// ---------------- launcher ----------------
extern "C" void kernel_launch(void* const* d_in, const int* in_sizes, int n_in,
                              void* d_out, int out_size, void* d_ws, size_t ws_size,
                              hipStream_t stream) {
    const float* x  = (const float*)d_in[0];
    const float* Wq = (const float*)d_in[1];
    const float* Wk = (const float*)d_in[2];
    const float* Wv = (const float*)d_in[3];
    float* out = (float*)d_out;
    char* wsb  = (char*)d_ws;

    // workspace layout (bytes), total ~27.4 MB
    float*    Q       = (float*)(wsb);                 //  8,388,608
    _Float16* Qh      = (_Float16*)(wsb + 8388608);    //  4,194,304
    _Float16* Kh      = (_Float16*)(wsb + 12582912);   //  4,194,304
    ushort_t* Vt      = (ushort_t*)(wsb + 16777216);   //  4,194,304 (f16)
    float*    pmean   = (float*)(wsb + 20971520);      //  131,072
    float*    meanfin = (float*)(wsb + 21102592);      //  2,048
    float*    Kred    = (float*)(wsb + 21104640);      //  2,048
    int*      sel     = (int*)(wsb + 21106688);        //  90,112
    int*      inv     = (int*)(wsb + 21196800);        //  131,072
    // alias region: Kt (8,388,608) until kmean consumes it; then pout+pl
    float*    Kt      = (float*)(wsb + 21327872);
    float*    pout    = (float*)(wsb + 21327872);      //  5,767,168
    float*    pl      = (float*)(wsb + 21327872 + 5767168);  // 90,112

    proj_kernel  <<<dim3(64, 8),          256,  0, stream>>>(x, Wq, Wk, Wv, Q, Kt,
                                                             Qh, Kh, Vt, pmean);
    kmean_kernel <<<512,                  256,  0, stream>>>(Kt, pmean, Kred, meanfin);
    select_kernel<<<8,                    1024, 0, stream>>>(Q, Kred, sel, inv);
    // Kt dead after kmean; zero the region for the attention atomics.
    (void)hipMemsetAsync(pout, 0, 5767168 + 90112, stream);
    attn_kernel  <<<dim3(NQB, KS, BATCH), 128,  0, stream>>>((const ushort_t*)Qh,
                                                             (const ushort_t*)Kh,
                                                             Vt, sel, pl, pout);
    comb_kernel  <<<2048,                 256,  0, stream>>>(pl, pout, inv, meanfin, out);
}

// Round 8
// 238.088 us; speedup vs baseline: 1.0373x; 1.0373x over previous
//
#include <hip/hip_runtime.h>
#include <math.h>

#define BATCH 8
#define SEQ   4096
#define DIM   64
#define LQ    2744            // int((1-0.33)*4096)
#define QPB   256             // queries per attn block (4 waves x 64)
#define NQB   11              // 2816/256
#define QPAD  2816
#define KS    8               // key splits (512 keys per block)
#define QSC   0.1803368801111204f   // 0.125 * log2(e), folded into Qh
#define PZN   1464320         // floats to zero in pout+pl region

typedef _Float16 half8 __attribute__((ext_vector_type(8)));
typedef __fp16   fp16x2 __attribute__((ext_vector_type(2)));
typedef float    fx16  __attribute__((ext_vector_type(16)));
typedef unsigned short ushort_t;

union UHF { unsigned u[4]; uint4 u4; half8 h; };

__device__ __forceinline__ unsigned pack_f16(float a, float b) {
    fp16x2 r = __builtin_amdgcn_cvt_pkrtz(a, b);   // v_cvt_pkrtz_f16_f32
    union { fp16x2 h; unsigned u; } cv; cv.h = r; return cv.u;
}

// ---------------- sortable-uint mapping ----------------
__device__ __forceinline__ unsigned f2sort(float f) {
    unsigned u = __float_as_uint(f);
    return (u & 0x80000000u) ? ~u : (u | 0x80000000u);
}
__device__ __forceinline__ float sort2f(unsigned u) {
    return __uint_as_float((u & 0x80000000u) ? (u & 0x7FFFFFFFu) : ~u);
}

// ---------------- radix select: k-th largest of 4096 (R4-measured-best) --
// LDS atomic histogram + 256-thread Hillis-Steele suffix scan.
// res[0] = key of k-th largest; res[1] = #elems equal to key in the top-k.
template <int NT>
__device__ void radix_select_4096(const unsigned* u, int k, unsigned* hist,
                                  unsigned* scan, unsigned* res) {
    const int t = threadIdx.x;
    if (t == 0) { res[0] = 0u; res[1] = (unsigned)k; }
    for (int pass = 3; pass >= 0; --pass) {
        const int shift = pass * 8;
        if (t < 256) hist[t] = 0u;
        __syncthreads();
        const unsigned pref  = res[0];
        const unsigned kk    = res[1];
        const unsigned hmask = (pass == 3) ? 0u : (0xFFFFFFFFu << (shift + 8));
        for (int i = t; i < 4096; i += NT) {
            unsigned ui = u[i];
            if ((ui & hmask) == pref) atomicAdd(&hist[(ui >> shift) & 255u], 1u);
        }
        __syncthreads();
        unsigned h = 0u, s = 0u;
        if (t < 256) { h = hist[t]; s = h; scan[t] = s; }
        __syncthreads();
#pragma unroll
        for (int ofs = 1; ofs < 256; ofs <<= 1) {
            unsigned add = (t < 256 && t + ofs < 256) ? scan[t + ofs] : 0u;
            __syncthreads();
            if (t < 256) { s += add; scan[t] = s; }
            __syncthreads();
        }
        if (t < 256 && s >= kk && (s - h) < kk) {   // unique threshold bin
            res[0] = pref | ((unsigned)t << shift);
            res[1] = kk - (s - h);
        }
        __syncthreads();
    }
}

// ---------------- K1: projections -------------------
// Q fp32 (selection path), Kt fp32 (channel top-k), Qh f16 scaled, Kh f16,
// Vt f16 transposed+k-permuted (PV B-fragment order), pmean partial V sums.
__global__ __launch_bounds__(256) void proj_kernel(
    const float* __restrict__ x,  const float* __restrict__ Wq,
    const float* __restrict__ Wk, const float* __restrict__ Wv,
    float* __restrict__ Q, float* __restrict__ Kt,
    _Float16* __restrict__ Qh, _Float16* __restrict__ Kh,
    ushort_t* __restrict__ Vt, float* __restrict__ pmean) {
    const int rt = blockIdx.x, b = blockIdx.y, t = threadIdx.x;
    __shared__ float4 xs4[64 * 17];
    __shared__ float  red[4][64];
    {
        const float4* xg = (const float4*)(x + ((size_t)b * SEQ + rt * 64) * DIM);
        for (int i = 0; i < 4; ++i) {
            int s = t + 256 * i;
            xs4[(s >> 4) * 17 + (s & 15)] = xg[s];
        }
    }
    __syncthreads();
    const int ch = t & 63, rg = t >> 6;
    float accq[16], acck[16], accv[16];
#pragma unroll
    for (int i = 0; i < 16; ++i) { accq[i] = 0.f; acck[i] = 0.f; accv[i] = 0.f; }
    for (int dc = 0; dc < 4; ++dc) {
        float wq[16], wk[16], wv[16];
#pragma unroll
        for (int dd = 0; dd < 16; ++dd) {
            int d = dc * 16 + dd;
            wq[dd] = Wq[d * 64 + ch]; wk[dd] = Wk[d * 64 + ch]; wv[dd] = Wv[d * 64 + ch];
        }
        for (int r = 0; r < 16; ++r) {
            const float4* xr = &xs4[(rg * 16 + r) * 17 + dc * 4];
            float xv[16];
            float4 a0 = xr[0], a1 = xr[1], a2 = xr[2], a3 = xr[3];
            xv[0]=a0.x; xv[1]=a0.y; xv[2]=a0.z; xv[3]=a0.w;
            xv[4]=a1.x; xv[5]=a1.y; xv[6]=a1.z; xv[7]=a1.w;
            xv[8]=a2.x; xv[9]=a2.y; xv[10]=a2.z; xv[11]=a2.w;
            xv[12]=a3.x; xv[13]=a3.y; xv[14]=a3.z; xv[15]=a3.w;
#pragma unroll
            for (int dd = 0; dd < 16; ++dd) {
                accq[r] = fmaf(xv[dd], wq[dd], accq[r]);
                acck[r] = fmaf(xv[dd], wk[dd], acck[r]);
                accv[r] = fmaf(xv[dd], wv[dd], accv[r]);
            }
        }
    }
    const int rowbase = rt * 64 + rg * 16;
    float sv = 0.f;
#pragma unroll
    for (int r = 0; r < 16; ++r) {
        size_t o = ((size_t)b * SEQ + rowbase + r) * DIM + ch;
        Q[o]  = accq[r];
        Qh[o] = (_Float16)(accq[r] * QSC);
        Kh[o] = (_Float16)acck[r];
        sv += accv[r];
    }
    float4* ktp = (float4*)(Kt + ((size_t)b * 64 + ch) * SEQ + rowbase);
    ktp[0] = make_float4(acck[0], acck[1], acck[2], acck[3]);
    ktp[1] = make_float4(acck[4], acck[5], acck[6], acck[7]);
    ktp[2] = make_float4(acck[8], acck[9], acck[10], acck[11]);
    ktp[3] = make_float4(acck[12], acck[13], acck[14], acck[15]);
    // Vt f16, k-permuted pair order within each 16-group: [0,1,4,5,2,3,6,7]
    {
        unsigned pk[8];
#pragma unroll
        for (int i = 0; i < 8; ++i) pk[i] = pack_f16(accv[2*i], accv[2*i+1]);
        uint4* vp = (uint4*)(Vt + ((size_t)(b * 64 + ch)) * SEQ + rowbase);
        vp[0] = make_uint4(pk[0], pk[1], pk[4], pk[5]);
        vp[1] = make_uint4(pk[2], pk[3], pk[6], pk[7]);
    }
    red[rg][ch] = sv;
    __syncthreads();
    if (rg == 0)
        pmean[((size_t)b * 64 + ch) * 64 + rt] =
            red[0][ch] + red[1][ch] + red[2][ch] + red[3][ch];
}

// ---------------- K2: K_reduce top-LQ mean; V-mean agg; zero pout --------
// Each block also zeroes its OWN Kt slice's overlap with the pout/pl
// region (Kt aliases pout) AFTER staging its data to LDS — this replaces
// the separate hipMemsetAsync dispatch.
__global__ __launch_bounds__(256) void kmean_kernel(const float* __restrict__ Kt,
                                                    const float* __restrict__ pmean,
                                                    float* __restrict__ Kred,
                                                    float* __restrict__ meanfin,
                                                    float* __restrict__ poutz) {
    __shared__ unsigned u[4096];
    __shared__ unsigned hist[256];
    __shared__ unsigned scan[256];
    __shared__ unsigned res[2];
    __shared__ float rsum[4];
    const int bc = blockIdx.x, t = threadIdx.x;
    if (t < 64) {   // V-mean aggregation: wave 0 sums the 64 partials
        float v = pmean[(size_t)bc * 64 + t];
        for (int m = 1; m < 64; m <<= 1) v += __shfl_xor(v, m, 64);
        if (t == 0) meanfin[bc] = v * (1.0f / (float)SEQ);
    }
    const float4* c4 = (const float4*)(Kt + (size_t)bc * SEQ);
    for (int i = t; i < 1024; i += 256) {
        float4 v = c4[i];
        u[i*4+0] = f2sort(v.x); u[i*4+1] = f2sort(v.y);
        u[i*4+2] = f2sort(v.z); u[i*4+3] = f2sort(v.w);
    }
    __syncthreads();
    // zero own slice of the pout/pl region (safe: own data staged above)
    {
        const int zbase = bc * 4096;
        if (zbase < PZN) {
            const int zend = (zbase + 4096 < PZN) ? zbase + 4096 : PZN;
            float4* z4 = (float4*)(poutz + zbase);
            const int n4 = (zend - zbase) >> 2;
            const float4 zz = make_float4(0.f, 0.f, 0.f, 0.f);
            for (int i = t; i < n4; i += 256) z4[i] = zz;
        }
    }
    radix_select_4096<256>(u, LQ, hist, scan, res);
    const unsigned Tu = res[0];
    const int krem = (int)res[1];
    float loc = 0.f;
    for (int i = t; i < 4096; i += 256)
        if (u[i] > Tu) loc += sort2f(u[i]);
    for (int msk = 1; msk < 64; msk <<= 1) loc += __shfl_xor(loc, msk, 64);
    if ((t & 63) == 0) rsum[t >> 6] = loc;
    __syncthreads();
    if (t == 0) {
        float s = rsum[0] + rsum[1] + rsum[2] + rsum[3] + (float)krem * sort2f(Tu);
        Kred[bc] = s / (float)LQ;
    }
}

// ---------------- K3: fused sqk + per-batch top-LQ selection -------------
__global__ __launch_bounds__(1024) void select_kernel(const float* __restrict__ Q,
                                                      const float* __restrict__ Kred,
                                                      int* __restrict__ sel,
                                                      int* __restrict__ inv) {
    __shared__ unsigned u[4096];
    __shared__ unsigned hist[256];
    __shared__ unsigned scan[256];
    __shared__ unsigned res[2];
    __shared__ float kr[64];
    __shared__ int eq_idx[256];
    __shared__ int cnts[2];
    const int b = blockIdx.x, t = threadIdx.x;
    if (t < 64) kr[t] = Kred[b * 64 + t];
    if (t < 2) cnts[t] = 0;
    int* invb = inv + (size_t)b * SEQ;
    __syncthreads();
    for (int row = t; row < 4096; row += 1024) {   // sqk inline (fp32-exact)
        const float4* q = (const float4*)(Q + ((size_t)b * SEQ + row) * DIM);
        float s = 0.f;
#pragma unroll
        for (int i = 0; i < 16; ++i) {
            float4 v = q[i];
            s = fmaf(v.x, kr[i*4+0], s); s = fmaf(v.y, kr[i*4+1], s);
            s = fmaf(v.z, kr[i*4+2], s); s = fmaf(v.w, kr[i*4+3], s);
        }
        u[row] = f2sort(s);
        invb[row] = -1;
    }
    __syncthreads();
    radix_select_4096<1024>(u, LQ, hist, scan, res);
    const unsigned Tu = res[0];
    const int krem = (int)res[1];
    int* selb = sel + b * QPAD;
    for (int i = t; i < 4096; i += 1024) {
        unsigned ui = u[i];
        if (ui > Tu) {
            int p = atomicAdd(&cnts[0], 1);
            selb[p] = i;
            invb[i] = p;
        } else if (ui == Tu) {
            int p = atomicAdd(&cnts[1], 1);
            if (p < 256) eq_idx[p] = i;
        }
    }
    __syncthreads();
    if (t == 0) {
        int ng = cnts[0];
        int ne = cnts[1] < 256 ? cnts[1] : 256;
        for (int i = 1; i < ne; ++i) {          // ties ~unique floats: ne≈1
            int v = eq_idx[i], j = i - 1;
            while (j >= 0 && eq_idx[j] > v) { eq_idx[j+1] = eq_idx[j]; --j; }
            eq_idx[j+1] = v;
        }
        for (int j = 0; j < krem; ++j) {
            selb[ng + j] = eq_idx[j];
            invb[eq_idx[j]] = ng + j;
        }
    }
    __syncthreads();
    if (t < QPAD - LQ) selb[LQ + t] = selb[LQ - 1];   // pad (parallel)
}

// ---------------- K4: barrier-free MFMA flash attention ------------------
// NO LDS, NO __syncthreads: each wave loads its K/V MFMA fragments directly
// from global (K/V working set = 8 MB, L2/LLC-resident). 64 q/wave, 4
// independent waves per 256-thr block, register double-buffer for the next
// key tile. KS=8 key splits; merge via fp32 atomicAdd into zeroed pout/pl.
// Fragment addressing (derived from the verified LDS-swizzle algebra):
//   kf[m](col,h) = Kh[(b*SEQ + k0 + col)*64 + 16m + 8h]          (16B/lane)
//   vf[i](col,h) = Vt[(b*64 + col + 32*(i>>1))*SEQ + k0 + 16*(i&1) + 8h]
__global__ __launch_bounds__(256, 2) void attn_kernel(
    const ushort_t* __restrict__ Qh, const ushort_t* __restrict__ Kh,
    const ushort_t* __restrict__ Vt, const int* __restrict__ sel,
    float* __restrict__ pl, float* __restrict__ pout) {
    const int qt = blockIdx.x, ks = blockIdx.y, b = blockIdx.z;
    const int t = threadIdx.x, w = t >> 6, lane = t & 63;
    const int col = lane & 31, h = lane >> 5;
    const int qbase = qt * QPB + w * 64;

    // persistent Q fragments for the two q-column-blocks (B-operand layout)
    half8 qfa[4], qfb[4];
    {
        const int rowa = sel[b * QPAD + qbase + col];
        const int rowb = sel[b * QPAD + qbase + 32 + col];
        const uint4* qga = (const uint4*)(Qh + ((size_t)b * SEQ + rowa) * DIM);
        const uint4* qgb = (const uint4*)(Qh + ((size_t)b * SEQ + rowb) * DIM);
#pragma unroll
        for (int m = 0; m < 4; ++m) {
            UHF ua, ub;
            ua.u4 = qga[2 * m + h]; qfa[m] = ua.h;
            ub.u4 = qgb[2 * m + h]; qfb[m] = ub.h;
        }
    }

    // per-lane fragment base pointers (advance by one 32-key tile each iter)
    const ushort_t* kp  = Kh + ((size_t)b * SEQ + ks * 512 + col) * 64 + 8 * h;
    const ushort_t* vpa = Vt + ((size_t)(b * 64 + col)) * SEQ + ks * 512 + 8 * h;
    const ushort_t* vpb = vpa + (size_t)32 * SEQ;

    fx16 Oa0, Oa1, Ob0, Ob1;
#pragma unroll
    for (int r = 0; r < 16; ++r) { Oa0[r]=0.f; Oa1[r]=0.f; Ob0[r]=0.f; Ob1[r]=0.f; }
    float la = 0.f, lb = 0.f;

    // prime the register double-buffer with tile 0
    uint4 kb0[4], vb0[4];
#pragma unroll
    for (int m = 0; m < 4; ++m) kb0[m] = *(const uint4*)(kp + 16 * m);
    vb0[0] = *(const uint4*)(vpa);      vb0[1] = *(const uint4*)(vpa + 16);
    vb0[2] = *(const uint4*)(vpb);      vb0[3] = *(const uint4*)(vpb + 16);

    for (int tile = 0; tile < 16; ++tile) {
        uint4 kc[4], vc[4];
#pragma unroll
        for (int m = 0; m < 4; ++m) { kc[m] = kb0[m]; vc[m] = vb0[m]; }
        if (tile < 15) {   // issue next-tile loads; they overlap the compute
            kp += 32 * 64; vpa += 32; vpb += 32;
#pragma unroll
            for (int m = 0; m < 4; ++m) kb0[m] = *(const uint4*)(kp + 16 * m);
            vb0[0] = *(const uint4*)(vpa);      vb0[1] = *(const uint4*)(vpa + 16);
            vb0[2] = *(const uint4*)(vpb);      vb0[3] = *(const uint4*)(vpb + 16);
        }
        // S^T tiles (two independent 4-MFMA chains)
        fx16 Sa, Sb;
#pragma unroll
        for (int r = 0; r < 16; ++r) { Sa[r] = 0.f; Sb[r] = 0.f; }
#pragma unroll
        for (int m = 0; m < 4; ++m) {
            UHF kf; kf.u4 = kc[m];
            Sa = __builtin_amdgcn_mfma_f32_32x32x16_f16(kf.h, qfa[m], Sa, 0, 0, 0);
            Sb = __builtin_amdgcn_mfma_f32_32x32x16_f16(kf.h, qfb[m], Sb, 0, 0, 0);
        }
        // exp2 + f16 pack + row-sum (P = exp2(S); no max: scores bounded)
        UHF Aa0, Aa1, Ab0, Ab1;
#pragma unroll
        for (int v = 0; v < 4; ++v) {
            float a0 = __builtin_amdgcn_exp2f(Sa[2*v]);
            float a1 = __builtin_amdgcn_exp2f(Sa[2*v+1]);
            float a2 = __builtin_amdgcn_exp2f(Sa[8+2*v]);
            float a3 = __builtin_amdgcn_exp2f(Sa[8+2*v+1]);
            la += (a0 + a1) + (a2 + a3);
            Aa0.u[v] = pack_f16(a0, a1);
            Aa1.u[v] = pack_f16(a2, a3);
            float b0 = __builtin_amdgcn_exp2f(Sb[2*v]);
            float b1 = __builtin_amdgcn_exp2f(Sb[2*v+1]);
            float b2 = __builtin_amdgcn_exp2f(Sb[8+2*v]);
            float b3 = __builtin_amdgcn_exp2f(Sb[8+2*v+1]);
            lb += (b0 + b1) + (b2 + b3);
            Ab0.u[v] = pack_f16(b0, b1);
            Ab1.u[v] = pack_f16(b2, b3);
        }
        // O += P * V (f16 MFMA, 4 independent accumulator chains)
        UHF vf0, vf1, vf2, vf3;
        vf0.u4 = vc[0]; vf1.u4 = vc[1]; vf2.u4 = vc[2]; vf3.u4 = vc[3];
        Oa0 = __builtin_amdgcn_mfma_f32_32x32x16_f16(Aa0.h, vf0.h, Oa0, 0, 0, 0);
        Ob0 = __builtin_amdgcn_mfma_f32_32x32x16_f16(Ab0.h, vf0.h, Ob0, 0, 0, 0);
        Oa0 = __builtin_amdgcn_mfma_f32_32x32x16_f16(Aa1.h, vf1.h, Oa0, 0, 0, 0);
        Ob0 = __builtin_amdgcn_mfma_f32_32x32x16_f16(Ab1.h, vf1.h, Ob0, 0, 0, 0);
        Oa1 = __builtin_amdgcn_mfma_f32_32x32x16_f16(Aa0.h, vf2.h, Oa1, 0, 0, 0);
        Ob1 = __builtin_amdgcn_mfma_f32_32x32x16_f16(Ab0.h, vf2.h, Ob1, 0, 0, 0);
        Oa1 = __builtin_amdgcn_mfma_f32_32x32x16_f16(Aa1.h, vf3.h, Oa1, 0, 0, 0);
        Ob1 = __builtin_amdgcn_mfma_f32_32x32x16_f16(Ab1.h, vf3.h, Ob1, 0, 0, 0);
    }

    la += __shfl_xor(la, 32);   // combine the two k-halves per column
    lb += __shfl_xor(lb, 32);

    const size_t base = (size_t)b * QPAD + qbase;
#pragma unroll
    for (int r = 0; r < 16; ++r) {
        const int q = (r & 3) + 8 * (r >> 2) + 4 * h;
        atomicAdd(&pout[(base + q) * DIM + col],           Oa0[r]);
        atomicAdd(&pout[(base + q) * DIM + 32 + col],      Oa1[r]);
        atomicAdd(&pout[(base + 32 + q) * DIM + col],      Ob0[r]);
        atomicAdd(&pout[(base + 32 + q) * DIM + 32 + col], Ob1[r]);
    }
    if (h == 0) {
        atomicAdd(&pl[base + col], la);
        atomicAdd(&pl[base + 32 + col], lb);
    }
}

// ---------------- K5: normalize+scatter OR mean-fill, one pass -----------
__global__ __launch_bounds__(256) void comb_kernel(
    const float* __restrict__ pl, const float* __restrict__ pout,
    const int* __restrict__ inv, const float* __restrict__ meanfin,
    float* __restrict__ out) {
    const int idx = blockIdx.x * 256 + threadIdx.x;   // over BATCH*SEQ*16
    const int b = idx >> 16;
    const int rc = idx & 65535;
    const int row = rc >> 4, c = rc & 15;
    const int p = inv[b * SEQ + row];
    float4 o;
    if (p >= 0) {
        const size_t s0 = (size_t)b * QPAD + p;
        const float invl = 1.0f / pl[s0];
        float4 a = ((const float4*)(pout + s0 * DIM))[c];
        o = make_float4(a.x * invl, a.y * invl, a.z * invl, a.w * invl);
    } else {
        o = make_float4(meanfin[b * 64 + c * 4 + 0], meanfin[b * 64 + c * 4 + 1],
                        meanfin[b * 64 + c * 4 + 2], meanfin[b * 64 + c * 4 + 3]);
    }
    ((float4*)out)[idx] = o;
}

// ---------------- launcher (5 dispatches) ----------------
extern "C" void kernel_launch(void* const* d_in, const int* in_sizes, int n_in,
                              void* d_out, int out_size, void* d_ws, size_t ws_size,
                              hipStream_t stream) {
    const float* x  = (const float*)d_in[0];
    const float* Wq = (const float*)d_in[1];
    const float* Wk = (const float*)d_in[2];
    const float* Wv = (const float*)d_in[3];
    float* out = (float*)d_out;
    char* wsb  = (char*)d_ws;

    // workspace layout (bytes), total ~29.7 MB
    float*    Q       = (float*)(wsb);                 //  8,388,608
    _Float16* Qh      = (_Float16*)(wsb + 8388608);    //  4,194,304
    _Float16* Kh      = (_Float16*)(wsb + 12582912);   //  4,194,304
    ushort_t* Vt      = (ushort_t*)(wsb + 16777216);   //  4,194,304 (f16)
    float*    pmean   = (float*)(wsb + 20971520);      //  131,072
    float*    meanfin = (float*)(wsb + 21102592);      //  2,048
    float*    Kred    = (float*)(wsb + 21104640);      //  2,048
    int*      sel     = (int*)(wsb + 21106688);        //  90,112
    int*      inv     = (int*)(wsb + 21196800);        //  131,072
    // alias region: Kt (8,388,608) until kmean consumes it; then pout+pl
    // (kmean zeroes the pout/pl overlap of its OWN slice after staging)
    float*    Kt      = (float*)(wsb + 21327872);
    float*    pout    = (float*)(wsb + 21327872);      //  5,767,168
    float*    pl      = (float*)(wsb + 21327872 + 5767168);  // 90,112

    proj_kernel  <<<dim3(64, 8),          256,  0, stream>>>(x, Wq, Wk, Wv, Q, Kt,
                                                             Qh, Kh, Vt, pmean);
    kmean_kernel <<<512,                  256,  0, stream>>>(Kt, pmean, Kred,
                                                             meanfin, pout);
    select_kernel<<<8,                    1024, 0, stream>>>(Q, Kred, sel, inv);
    attn_kernel  <<<dim3(NQB, KS, BATCH), 256,  0, stream>>>((const ushort_t*)Qh,
                                                             (const ushort_t*)Kh,
                                                             Vt, sel, pl, pout);
    comb_kernel  <<<2048,                 256,  0, stream>>>(pl, pout, inv, meanfin, out);
}

// Round 9
// 209.016 us; speedup vs baseline: 1.1815x; 1.1391x over previous
//
#include <hip/hip_runtime.h>
#include <math.h>

#define BATCH 8
#define SEQ   4096
#define DIM   64
#define LQ    2744            // int((1-0.33)*4096)
#define QPB   128             // queries per attn block (4 waves x 32)
#define NQB   22              // 2816/128
#define QPAD  2816
#define KS    8               // key splits (512 keys per block)
#define QSC   0.1803368801111204f   // 0.125 * log2(e), folded into Qh
#define PZN   1464320         // floats to zero in pout+pl region

typedef _Float16 half8 __attribute__((ext_vector_type(8)));
typedef __fp16   fp16x2 __attribute__((ext_vector_type(2)));
typedef float    fx16  __attribute__((ext_vector_type(16)));
typedef unsigned short ushort_t;

union UHF { unsigned u[4]; uint4 u4; half8 h; };

__device__ __forceinline__ unsigned pack_f16(float a, float b) {
    fp16x2 r = __builtin_amdgcn_cvt_pkrtz(a, b);   // v_cvt_pkrtz_f16_f32
    union { fp16x2 h; unsigned u; } cv; cv.h = r; return cv.u;
}

// ---------------- sortable-uint mapping ----------------
__device__ __forceinline__ unsigned f2sort(float f) {
    unsigned u = __float_as_uint(f);
    return (u & 0x80000000u) ? ~u : (u | 0x80000000u);
}
__device__ __forceinline__ float sort2f(unsigned u) {
    return __uint_as_float((u & 0x80000000u) ? (u & 0x7FFFFFFFu) : ~u);
}

// ---------------- radix select: k-th largest of 4096 (R4-measured-best) --
// LDS atomic histogram + 256-thread Hillis-Steele suffix scan.
// res[0] = key of k-th largest; res[1] = #elems equal to key in the top-k.
template <int NT>
__device__ void radix_select_4096(const unsigned* u, int k, unsigned* hist,
                                  unsigned* scan, unsigned* res) {
    const int t = threadIdx.x;
    if (t == 0) { res[0] = 0u; res[1] = (unsigned)k; }
    for (int pass = 3; pass >= 0; --pass) {
        const int shift = pass * 8;
        if (t < 256) hist[t] = 0u;
        __syncthreads();
        const unsigned pref  = res[0];
        const unsigned kk    = res[1];
        const unsigned hmask = (pass == 3) ? 0u : (0xFFFFFFFFu << (shift + 8));
        for (int i = t; i < 4096; i += NT) {
            unsigned ui = u[i];
            if ((ui & hmask) == pref) atomicAdd(&hist[(ui >> shift) & 255u], 1u);
        }
        __syncthreads();
        unsigned h = 0u, s = 0u;
        if (t < 256) { h = hist[t]; s = h; scan[t] = s; }
        __syncthreads();
#pragma unroll
        for (int ofs = 1; ofs < 256; ofs <<= 1) {
            unsigned add = (t < 256 && t + ofs < 256) ? scan[t + ofs] : 0u;
            __syncthreads();
            if (t < 256) { s += add; scan[t] = s; }
            __syncthreads();
        }
        if (t < 256 && s >= kk && (s - h) < kk) {   // unique threshold bin
            res[0] = pref | ((unsigned)t << shift);
            res[1] = kk - (s - h);
        }
        __syncthreads();
    }
}

// ---------------- K1: projections -------------------
// Q fp32 (selection path), Kt fp32 (channel top-k), Qh f16 scaled, Kh f16,
// Vt f16 transposed+k-permuted (PV B-fragment order), pmean partial V sums.
__global__ __launch_bounds__(256) void proj_kernel(
    const float* __restrict__ x,  const float* __restrict__ Wq,
    const float* __restrict__ Wk, const float* __restrict__ Wv,
    float* __restrict__ Q, float* __restrict__ Kt,
    _Float16* __restrict__ Qh, _Float16* __restrict__ Kh,
    ushort_t* __restrict__ Vt, float* __restrict__ pmean) {
    const int rt = blockIdx.x, b = blockIdx.y, t = threadIdx.x;
    __shared__ float4 xs4[64 * 17];
    __shared__ float  red[4][64];
    {
        const float4* xg = (const float4*)(x + ((size_t)b * SEQ + rt * 64) * DIM);
        for (int i = 0; i < 4; ++i) {
            int s = t + 256 * i;
            xs4[(s >> 4) * 17 + (s & 15)] = xg[s];
        }
    }
    __syncthreads();
    const int ch = t & 63, rg = t >> 6;
    float accq[16], acck[16], accv[16];
#pragma unroll
    for (int i = 0; i < 16; ++i) { accq[i] = 0.f; acck[i] = 0.f; accv[i] = 0.f; }
    for (int dc = 0; dc < 4; ++dc) {
        float wq[16], wk[16], wv[16];
#pragma unroll
        for (int dd = 0; dd < 16; ++dd) {
            int d = dc * 16 + dd;
            wq[dd] = Wq[d * 64 + ch]; wk[dd] = Wk[d * 64 + ch]; wv[dd] = Wv[d * 64 + ch];
        }
        for (int r = 0; r < 16; ++r) {
            const float4* xr = &xs4[(rg * 16 + r) * 17 + dc * 4];
            float xv[16];
            float4 a0 = xr[0], a1 = xr[1], a2 = xr[2], a3 = xr[3];
            xv[0]=a0.x; xv[1]=a0.y; xv[2]=a0.z; xv[3]=a0.w;
            xv[4]=a1.x; xv[5]=a1.y; xv[6]=a1.z; xv[7]=a1.w;
            xv[8]=a2.x; xv[9]=a2.y; xv[10]=a2.z; xv[11]=a2.w;
            xv[12]=a3.x; xv[13]=a3.y; xv[14]=a3.z; xv[15]=a3.w;
#pragma unroll
            for (int dd = 0; dd < 16; ++dd) {
                accq[r] = fmaf(xv[dd], wq[dd], accq[r]);
                acck[r] = fmaf(xv[dd], wk[dd], acck[r]);
                accv[r] = fmaf(xv[dd], wv[dd], accv[r]);
            }
        }
    }
    const int rowbase = rt * 64 + rg * 16;
    float sv = 0.f;
#pragma unroll
    for (int r = 0; r < 16; ++r) {
        size_t o = ((size_t)b * SEQ + rowbase + r) * DIM + ch;
        Q[o]  = accq[r];
        Qh[o] = (_Float16)(accq[r] * QSC);
        Kh[o] = (_Float16)acck[r];
        sv += accv[r];
    }
    float4* ktp = (float4*)(Kt + ((size_t)b * 64 + ch) * SEQ + rowbase);
    ktp[0] = make_float4(acck[0], acck[1], acck[2], acck[3]);
    ktp[1] = make_float4(acck[4], acck[5], acck[6], acck[7]);
    ktp[2] = make_float4(acck[8], acck[9], acck[10], acck[11]);
    ktp[3] = make_float4(acck[12], acck[13], acck[14], acck[15]);
    // Vt f16, k-permuted pair order within each 16-group: [0,1,4,5,2,3,6,7]
    {
        unsigned pk[8];
#pragma unroll
        for (int i = 0; i < 8; ++i) pk[i] = pack_f16(accv[2*i], accv[2*i+1]);
        uint4* vp = (uint4*)(Vt + ((size_t)(b * 64 + ch)) * SEQ + rowbase);
        vp[0] = make_uint4(pk[0], pk[1], pk[4], pk[5]);
        vp[1] = make_uint4(pk[2], pk[3], pk[6], pk[7]);
    }
    red[rg][ch] = sv;
    __syncthreads();
    if (rg == 0)
        pmean[((size_t)b * 64 + ch) * 64 + rt] =
            red[0][ch] + red[1][ch] + red[2][ch] + red[3][ch];
}

// ---------------- K2: K_reduce top-LQ mean; V-mean agg; zero pout --------
// Each block zeroes its OWN Kt slice's overlap with the pout/pl region
// (Kt aliases pout) AFTER staging its data to LDS — replaces the memset.
__global__ __launch_bounds__(256) void kmean_kernel(const float* __restrict__ Kt,
                                                    const float* __restrict__ pmean,
                                                    float* __restrict__ Kred,
                                                    float* __restrict__ meanfin,
                                                    float* __restrict__ poutz) {
    __shared__ unsigned u[4096];
    __shared__ unsigned hist[256];
    __shared__ unsigned scan[256];
    __shared__ unsigned res[2];
    __shared__ float rsum[4];
    const int bc = blockIdx.x, t = threadIdx.x;
    if (t < 64) {   // V-mean aggregation: wave 0 sums the 64 partials
        float v = pmean[(size_t)bc * 64 + t];
        for (int m = 1; m < 64; m <<= 1) v += __shfl_xor(v, m, 64);
        if (t == 0) meanfin[bc] = v * (1.0f / (float)SEQ);
    }
    const float4* c4 = (const float4*)(Kt + (size_t)bc * SEQ);
    for (int i = t; i < 1024; i += 256) {
        float4 v = c4[i];
        u[i*4+0] = f2sort(v.x); u[i*4+1] = f2sort(v.y);
        u[i*4+2] = f2sort(v.z); u[i*4+3] = f2sort(v.w);
    }
    __syncthreads();
    // zero own slice of the pout/pl region (safe: own data staged above)
    {
        const int zbase = bc * 4096;
        if (zbase < PZN) {
            const int zend = (zbase + 4096 < PZN) ? zbase + 4096 : PZN;
            float4* z4 = (float4*)(poutz + zbase);
            const int n4 = (zend - zbase) >> 2;
            const float4 zz = make_float4(0.f, 0.f, 0.f, 0.f);
            for (int i = t; i < n4; i += 256) z4[i] = zz;
        }
    }
    radix_select_4096<256>(u, LQ, hist, scan, res);
    const unsigned Tu = res[0];
    const int krem = (int)res[1];
    float loc = 0.f;
    for (int i = t; i < 4096; i += 256)
        if (u[i] > Tu) loc += sort2f(u[i]);
    for (int msk = 1; msk < 64; msk <<= 1) loc += __shfl_xor(loc, msk, 64);
    if ((t & 63) == 0) rsum[t >> 6] = loc;
    __syncthreads();
    if (t == 0) {
        float s = rsum[0] + rsum[1] + rsum[2] + rsum[3] + (float)krem * sort2f(Tu);
        Kred[bc] = s / (float)LQ;
    }
}

// ---------------- K3: fused sqk + per-batch top-LQ selection (256 thr) ---
__global__ __launch_bounds__(256) void select_kernel(const float* __restrict__ Q,
                                                     const float* __restrict__ Kred,
                                                     int* __restrict__ sel,
                                                     int* __restrict__ inv) {
    __shared__ unsigned u[4096];
    __shared__ unsigned hist[256];
    __shared__ unsigned scan[256];
    __shared__ unsigned res[2];
    __shared__ float kr[64];
    __shared__ int eq_idx[256];
    __shared__ int cnts[2];
    const int b = blockIdx.x, t = threadIdx.x;
    if (t < 64) kr[t] = Kred[b * 64 + t];
    if (t < 2) cnts[t] = 0;
    int* invb = inv + (size_t)b * SEQ;
    __syncthreads();
    for (int row = t; row < 4096; row += 256) {   // sqk inline (fp32-exact)
        const float4* q = (const float4*)(Q + ((size_t)b * SEQ + row) * DIM);
        float s = 0.f;
#pragma unroll
        for (int i = 0; i < 16; ++i) {
            float4 v = q[i];
            s = fmaf(v.x, kr[i*4+0], s); s = fmaf(v.y, kr[i*4+1], s);
            s = fmaf(v.z, kr[i*4+2], s); s = fmaf(v.w, kr[i*4+3], s);
        }
        u[row] = f2sort(s);
        invb[row] = -1;
    }
    __syncthreads();
    radix_select_4096<256>(u, LQ, hist, scan, res);
    const unsigned Tu = res[0];
    const int krem = (int)res[1];
    int* selb = sel + b * QPAD;
    for (int i = t; i < 4096; i += 256) {
        unsigned ui = u[i];
        if (ui > Tu) {
            int p = atomicAdd(&cnts[0], 1);
            selb[p] = i;
            invb[i] = p;
        } else if (ui == Tu) {
            int p = atomicAdd(&cnts[1], 1);
            if (p < 256) eq_idx[p] = i;
        }
    }
    __syncthreads();
    if (t == 0) {
        int ng = cnts[0];
        int ne = cnts[1] < 256 ? cnts[1] : 256;
        for (int i = 1; i < ne; ++i) {          // ties ~unique floats: ne≈1
            int v = eq_idx[i], j = i - 1;
            while (j >= 0 && eq_idx[j] > v) { eq_idx[j+1] = eq_idx[j]; --j; }
            eq_idx[j+1] = v;
        }
        for (int j = 0; j < krem; ++j) {
            selb[ng + j] = eq_idx[j];
            invb[eq_idx[j]] = ng + j;
        }
    }
    __syncthreads();
    if (t < QPAD - LQ) selb[LQ + t] = selb[LQ - 1];   // pad (parallel)
}

// ---------------- K4: MFMA flash attention (R5-measured-best structure) --
// 32 q/wave, 4 independent waves per 256-thr block, LDS double-buffer with
// ONE barrier per 32-key tile, KS=8 key splits. f16 P*V (1-op pkrtz pack).
// Key-split merge via global fp32 atomicAdd into zeroed pout/pl.
__global__ __launch_bounds__(256, 3) void attn_kernel(
    const ushort_t* __restrict__ Qh, const ushort_t* __restrict__ Kh,
    const ushort_t* __restrict__ Vt, const int* __restrict__ sel,
    float* __restrict__ pl, float* __restrict__ pout) {
    const int qt = blockIdx.x, ks = blockIdx.y, b = blockIdx.z;
    const int t = threadIdx.x, w = t >> 6, lane = t & 63;
    const int col = lane & 31, h = lane >> 5;

    __shared__ ushort_t Ktile[2][32 * 64];
    __shared__ ushort_t Vtile[2][32 * 64];

    // persistent Q fragments (B-operand: lane holds q=col, d=16m+8h+j)
    half8 qf[4];
    {
        const int q = qt * QPB + w * 32 + col;
        const int row = sel[b * QPAD + q];
        const uint4* qg = (const uint4*)(Qh + ((size_t)b * SEQ + row) * DIM);
#pragma unroll
        for (int m = 0; m < 4; ++m) { UHF u; u.u4 = qg[2 * m + h]; qf[m] = u.h; }
    }

    // loop-invariant swizzled LDS offsets (ushort elements)
    int koff[4], voff[4];
#pragma unroll
    for (int m = 0; m < 4; ++m)
        koff[m] = col * 64 + 8 * ((2 * m + h) ^ (col & 7));
#pragma unroll
    for (int i = 0; i < 4; ++i)
        voff[i] = col * 64 + 8 * ((i * 2 + h) ^ (col & 7));   // i=2D+c

    fx16 O0, O1;
#pragma unroll
    for (int r = 0; r < 16; ++r) { O0[r] = 0.f; O1[r] = 0.f; }
    float l = 0.f;

    const int srow = t >> 3, sgr = t & 7;
    const int lg = sgr ^ (srow & 7);
    const int vD = lg >> 2, vc = (lg >> 1) & 1, vh = lg & 1;
    const size_t kgbase = ((size_t)b * SEQ + ks * 512 + srow) * DIM + 8 * lg;
    const size_t vgbase = ((size_t)(b * DIM + srow + 32 * vD)) * SEQ
                          + ks * 512 + vc * 16 + vh * 8;

    uint4 kreg = *(const uint4*)(Kh + kgbase);
    uint4 vreg = *(const uint4*)(Vt + vgbase);

    for (int tile = 0; tile < 16; ++tile) {
        const int buf = tile & 1;
        *(uint4*)&Ktile[buf][srow * 64 + sgr * 8] = kreg;
        *(uint4*)&Vtile[buf][srow * 64 + sgr * 8] = vreg;
        __syncthreads();
        if (tile < 15) {   // prefetch next tile during compute
            kreg = *(const uint4*)(Kh + kgbase + (size_t)(tile + 1) * 32 * DIM);
            vreg = *(const uint4*)(Vt + vgbase + (size_t)(tile + 1) * 32);
        }
        // S^T = K * Q^T  (f16 MFMA); Qh pre-scaled by 0.125*log2e
        fx16 S;
#pragma unroll
        for (int r = 0; r < 16; ++r) S[r] = 0.f;
#pragma unroll
        for (int m = 0; m < 4; ++m) {
            UHF kf;
            kf.u4 = *(const uint4*)&Ktile[buf][koff[m]];
            S = __builtin_amdgcn_mfma_f32_32x32x16_f16(kf.h, qf[m], S, 0, 0, 0);
        }
        // softmax numerators (raw v_exp_f32; scores bounded « 128)
        float p[16];
#pragma unroll
        for (int r = 0; r < 16; ++r) p[r] = __builtin_amdgcn_exp2f(S[r]);
#pragma unroll
        for (int r = 0; r < 16; ++r) l += p[r];
        UHF A0, A1;
#pragma unroll
        for (int v = 0; v < 4; ++v) {
            A0.u[v] = pack_f16(p[2 * v],     p[2 * v + 1]);
            A1.u[v] = pack_f16(p[8 + 2 * v], p[8 + 2 * v + 1]);
        }
        // O += P * V  (f16 MFMA)
#pragma unroll
        for (int D = 0; D < 2; ++D) {
            fx16& O = D ? O1 : O0;
#pragma unroll
            for (int c = 0; c < 2; ++c) {
                UHF vf;
                vf.u4 = *(const uint4*)&Vtile[buf][voff[D * 2 + c]];
                O = __builtin_amdgcn_mfma_f32_32x32x16_f16(c ? A1.h : A0.h, vf.h, O, 0, 0, 0);
            }
        }
    }

    l += __shfl_xor(l, 32);   // combine the two k-halves of the column sum

    const int qg0 = qt * QPB + w * 32;
    const size_t base = (size_t)b * QPAD + qg0;
#pragma unroll
    for (int D = 0; D < 2; ++D) {
        const fx16& O = D ? O1 : O0;
#pragma unroll
        for (int r = 0; r < 16; ++r) {
            const int q = (r & 3) + 8 * (r >> 2) + 4 * h;
            atomicAdd(&pout[(base + q) * DIM + D * 32 + col], O[r]);
        }
    }
    if (h == 0) atomicAdd(&pl[base + col], l);
}

// ---------------- K5: normalize+scatter OR mean-fill, one pass -----------
__global__ __launch_bounds__(256) void comb_kernel(
    const float* __restrict__ pl, const float* __restrict__ pout,
    const int* __restrict__ inv, const float* __restrict__ meanfin,
    float* __restrict__ out) {
    const int idx = blockIdx.x * 256 + threadIdx.x;   // over BATCH*SEQ*16
    const int b = idx >> 16;
    const int rc = idx & 65535;
    const int row = rc >> 4, c = rc & 15;
    const int p = inv[b * SEQ + row];
    float4 o;
    if (p >= 0) {
        const size_t s0 = (size_t)b * QPAD + p;
        const float invl = 1.0f / pl[s0];
        float4 a = ((const float4*)(pout + s0 * DIM))[c];
        o = make_float4(a.x * invl, a.y * invl, a.z * invl, a.w * invl);
    } else {
        o = make_float4(meanfin[b * 64 + c * 4 + 0], meanfin[b * 64 + c * 4 + 1],
                        meanfin[b * 64 + c * 4 + 2], meanfin[b * 64 + c * 4 + 3]);
    }
    ((float4*)out)[idx] = o;
}

// ---------------- launcher (5 dispatches) ----------------
extern "C" void kernel_launch(void* const* d_in, const int* in_sizes, int n_in,
                              void* d_out, int out_size, void* d_ws, size_t ws_size,
                              hipStream_t stream) {
    const float* x  = (const float*)d_in[0];
    const float* Wq = (const float*)d_in[1];
    const float* Wk = (const float*)d_in[2];
    const float* Wv = (const float*)d_in[3];
    float* out = (float*)d_out;
    char* wsb  = (char*)d_ws;

    // workspace layout (bytes), total ~29.7 MB
    float*    Q       = (float*)(wsb);                 //  8,388,608
    _Float16* Qh      = (_Float16*)(wsb + 8388608);    //  4,194,304
    _Float16* Kh      = (_Float16*)(wsb + 12582912);   //  4,194,304
    ushort_t* Vt      = (ushort_t*)(wsb + 16777216);   //  4,194,304 (f16)
    float*    pmean   = (float*)(wsb + 20971520);      //  131,072
    float*    meanfin = (float*)(wsb + 21102592);      //  2,048
    float*    Kred    = (float*)(wsb + 21104640);      //  2,048
    int*      sel     = (int*)(wsb + 21106688);        //  90,112
    int*      inv     = (int*)(wsb + 21196800);        //  131,072
    // alias region: Kt (8,388,608) until kmean consumes it; then pout+pl
    // (kmean zeroes the pout/pl overlap of its OWN slice after staging)
    float*    Kt      = (float*)(wsb + 21327872);
    float*    pout    = (float*)(wsb + 21327872);      //  5,767,168
    float*    pl      = (float*)(wsb + 21327872 + 5767168);  // 90,112

    proj_kernel  <<<dim3(64, 8),          256, 0, stream>>>(x, Wq, Wk, Wv, Q, Kt,
                                                            Qh, Kh, Vt, pmean);
    kmean_kernel <<<512,                  256, 0, stream>>>(Kt, pmean, Kred,
                                                            meanfin, pout);
    select_kernel<<<8,                    256, 0, stream>>>(Q, Kred, sel, inv);
    attn_kernel  <<<dim3(NQB, KS, BATCH), 256, 0, stream>>>((const ushort_t*)Qh,
                                                            (const ushort_t*)Kh,
                                                            Vt, sel, pl, pout);
    comb_kernel  <<<2048,                 256, 0, stream>>>(pl, pout, inv, meanfin, out);
}